// Round 3
// baseline (343.042 us; speedup 1.0000x reference)
//
#include <hip/hip_runtime.h>

typedef __attribute__((ext_vector_type(8))) __bf16 bf16x8;
typedef __attribute__((ext_vector_type(4))) float f32x4;
typedef __attribute__((ext_vector_type(16))) float f32x16;

#define B_ROWS 8192
#define D_DIM  1024
#define K_DIM  2048
#define NG     5120

typedef const __attribute__((address_space(1))) void cg_void;
typedef __attribute__((address_space(3))) void lds_void;

__device__ __forceinline__ float bf2f(unsigned short u) {
    union { unsigned int ui; float f; } c; c.ui = ((unsigned int)u) << 16; return c.f;
}
__device__ __forceinline__ unsigned short f2bf(float f) {
    unsigned int u = __float_as_uint(f);
    unsigned int r = u + 0x7fffu + ((u >> 16) & 1u);
    return (unsigned short)(r >> 16);
}
__device__ __forceinline__ float sigm(float v) { return 1.0f / (1.0f + __expf(-v)); }

// ---------------- weight f32 -> bf16 convert ----------------
__global__ __launch_bounds__(256) void cvt_f32_bf16(const float* __restrict__ in,
                                                    unsigned short* __restrict__ out, int n4) {
    int i = blockIdx.x * 256 + threadIdx.x;
    if (i >= n4) return;
    float4 v = reinterpret_cast<const float4*>(in)[i];
    ushort4 o;
    o.x = f2bf(v.x); o.y = f2bf(v.y); o.z = f2bf(v.z); o.w = f2bf(v.w);
    reinterpret_cast<ushort4*>(out)[i] = o;
}

// ---------------- LN1: concat(x,h) -> layernorm -> bf16 ----------------
__global__ __launch_bounds__(256) void ln1_kernel(const float* __restrict__ x, const float* __restrict__ h,
                                                  const float* __restrict__ w, const float* __restrict__ b,
                                                  unsigned short* __restrict__ out) {
    const int row = blockIdx.x;
    const int t = threadIdx.x;
    const float4 xv = reinterpret_cast<const float4*>(x + (size_t)row * D_DIM)[t];
    const float4 hv = reinterpret_cast<const float4*>(h + (size_t)row * D_DIM)[t];
    float s  = xv.x + xv.y + xv.z + xv.w + hv.x + hv.y + hv.z + hv.w;
    float s2 = xv.x*xv.x + xv.y*xv.y + xv.z*xv.z + xv.w*xv.w
             + hv.x*hv.x + hv.y*hv.y + hv.z*hv.z + hv.w*hv.w;
#pragma unroll
    for (int off = 32; off > 0; off >>= 1) { s += __shfl_xor(s, off); s2 += __shfl_xor(s2, off); }
    __shared__ float red[8];
    const int wid = t >> 6, lane = t & 63;
    if (lane == 0) { red[wid] = s; red[4 + wid] = s2; }
    __syncthreads();
    s  = red[0] + red[1] + red[2] + red[3];
    s2 = red[4] + red[5] + red[6] + red[7];
    const float mu  = s * (1.0f / K_DIM);
    const float var = s2 * (1.0f / K_DIM) - mu * mu;
    const float inv = rsqrtf(var + 1e-5f);
    const float4 w0 = reinterpret_cast<const float4*>(w)[t];
    const float4 b0 = reinterpret_cast<const float4*>(b)[t];
    const float4 w1 = reinterpret_cast<const float4*>(w + D_DIM)[t];
    const float4 b1 = reinterpret_cast<const float4*>(b + D_DIM)[t];
    ushort4 o0, o1;
    o0.x = f2bf((xv.x - mu) * inv * w0.x + b0.x);
    o0.y = f2bf((xv.y - mu) * inv * w0.y + b0.y);
    o0.z = f2bf((xv.z - mu) * inv * w0.z + b0.z);
    o0.w = f2bf((xv.w - mu) * inv * w0.w + b0.w);
    o1.x = f2bf((hv.x - mu) * inv * w1.x + b1.x);
    o1.y = f2bf((hv.y - mu) * inv * w1.y + b1.y);
    o1.z = f2bf((hv.z - mu) * inv * w1.z + b1.z);
    o1.w = f2bf((hv.w - mu) * inv * w1.w + b1.w);
    reinterpret_cast<ushort4*>(out + (size_t)row * K_DIM)[t] = o0;
    reinterpret_cast<ushort4*>(out + (size_t)row * K_DIM + D_DIM)[t] = o1;
}

// ---------------- gate sigmoid + LN2 -> bf16 inp2 ----------------
__global__ __launch_bounds__(256) void gate_ln2_kernel(const float* __restrict__ x, const float* __restrict__ h,
                                                       const unsigned short* __restrict__ gates,
                                                       const float* __restrict__ w, const float* __restrict__ b,
                                                       unsigned short* __restrict__ out) {
    const int row = blockIdx.x;
    const int t = threadIdx.x;
    const float4 xv = reinterpret_cast<const float4*>(x + (size_t)row * D_DIM)[t];
    const float4 hv = reinterpret_cast<const float4*>(h + (size_t)row * D_DIM)[t];
    const ushort4 g0v = reinterpret_cast<const ushort4*>(gates + (size_t)row * NG)[t];
    const ushort4 g1v = reinterpret_cast<const ushort4*>(gates + (size_t)row * NG + D_DIM)[t];
    float a0 = xv.x * sigm(bf2f(g0v.x));
    float a1 = xv.y * sigm(bf2f(g0v.y));
    float a2 = xv.z * sigm(bf2f(g0v.z));
    float a3 = xv.w * sigm(bf2f(g0v.w));
    float c0 = hv.x * sigm(bf2f(g1v.x));
    float c1 = hv.y * sigm(bf2f(g1v.y));
    float c2 = hv.z * sigm(bf2f(g1v.z));
    float c3 = hv.w * sigm(bf2f(g1v.w));
    float s  = a0 + a1 + a2 + a3 + c0 + c1 + c2 + c3;
    float s2 = a0*a0 + a1*a1 + a2*a2 + a3*a3 + c0*c0 + c1*c1 + c2*c2 + c3*c3;
#pragma unroll
    for (int off = 32; off > 0; off >>= 1) { s += __shfl_xor(s, off); s2 += __shfl_xor(s2, off); }
    __shared__ float red[8];
    const int wid = t >> 6, lane = t & 63;
    if (lane == 0) { red[wid] = s; red[4 + wid] = s2; }
    __syncthreads();
    s  = red[0] + red[1] + red[2] + red[3];
    s2 = red[4] + red[5] + red[6] + red[7];
    const float mu  = s * (1.0f / K_DIM);
    const float var = s2 * (1.0f / K_DIM) - mu * mu;
    const float inv = rsqrtf(var + 1e-5f);
    const float4 w0 = reinterpret_cast<const float4*>(w)[t];
    const float4 b0 = reinterpret_cast<const float4*>(b)[t];
    const float4 w1 = reinterpret_cast<const float4*>(w + D_DIM)[t];
    const float4 b1 = reinterpret_cast<const float4*>(b + D_DIM)[t];
    ushort4 o0, o1;
    o0.x = f2bf((a0 - mu) * inv * w0.x + b0.x);
    o0.y = f2bf((a1 - mu) * inv * w0.y + b0.y);
    o0.z = f2bf((a2 - mu) * inv * w0.z + b0.z);
    o0.w = f2bf((a3 - mu) * inv * w0.w + b0.w);
    o1.x = f2bf((c0 - mu) * inv * w1.x + b1.x);
    o1.y = f2bf((c1 - mu) * inv * w1.y + b1.y);
    o1.z = f2bf((c2 - mu) * inv * w1.z + b1.z);
    o1.w = f2bf((c3 - mu) * inv * w1.w + b1.w);
    reinterpret_cast<ushort4*>(out + (size_t)row * K_DIM)[t] = o0;
    reinterpret_cast<ushort4*>(out + (size_t)row * K_DIM + D_DIM)[t] = o1;
}

// ---------------- GEMM1: 256x256 8-phase pipelined, 32x32x16 MFMA ----------------
// Sync structure (phases / stagger / vmcnt ledger / barriers) identical to the
// round-2 race-verified version; only MFMA shape + frag addressing + epilogue changed.
// A-frag (32x32x16): row = base + (lane&31), k = (lane>>5)*8 + j  -> byteIn = (lane>>5)*16 + gks*32
// C/D: col = lane&31, row = (reg&3) + 8*(reg>>2) + 4*(lane>>5)   [m74/m101]
#define PH32(BUF, H, KP, LOADB, STAGE_CODE, VMCNT_CODE) do {                                          \
    bf16x8 aF[2][2];                                                                                  \
    _Pragma("unroll")                                                                                 \
    for (int m = 0; m < 2; ++m)                                                                       \
        _Pragma("unroll")                                                                             \
        for (int ks = 0; ks < 2; ++ks)                                                                \
            aF[m][ks] = *reinterpret_cast<const bf16x8*>(                                             \
                &smem[((BUF) * 2 + (H)) * 8192 + ((aRdS[m] ^ (((KP) * 2 + ks) * 32)) >> 1)]);         \
    if (LOADB) {                                                                                      \
        _Pragma("unroll")                                                                             \
        for (int n = 0; n < 2; ++n)                                                                   \
            _Pragma("unroll")                                                                         \
            for (int ks = 0; ks < 2; ++ks)                                                            \
                bF[(KP) * 2 + ks][n] = *reinterpret_cast<const bf16x8*>(                              \
                    &smem[32768 + ((BUF) * 2 + bHalf) * 8192 +                                        \
                          ((bRdS[n] ^ (((KP) * 2 + ks) * 32)) >> 1)]);                                \
    }                                                                                                 \
    STAGE_CODE;                                                                                       \
    VMCNT_CODE;                                                                                       \
    asm volatile("" ::: "memory");                                                                    \
    __builtin_amdgcn_s_barrier();                                                                     \
    asm volatile("" ::: "memory");                                                                    \
    __builtin_amdgcn_s_setprio(1);                                                                    \
    _Pragma("unroll")                                                                                 \
    for (int m = 0; m < 2; ++m)                                                                       \
        _Pragma("unroll")                                                                             \
        for (int n = 0; n < 2; ++n)                                                                   \
            _Pragma("unroll")                                                                         \
            for (int ks = 0; ks < 2; ++ks)                                                            \
                acc[(H) * 4 + m * 2 + n] = __builtin_amdgcn_mfma_f32_32x32x16_bf16(                   \
                    aF[m][ks], bF[(KP) * 2 + ks][n], acc[(H) * 4 + m * 2 + n], 0, 0, 0);              \
    __builtin_amdgcn_s_setprio(0);                                                                    \
    asm volatile("" ::: "memory");                                                                    \
    __builtin_amdgcn_s_barrier();                                                                     \
    asm volatile("" ::: "memory");                                                                    \
} while (0)

#define VMC4 asm volatile("s_waitcnt vmcnt(4)" ::: "memory")
#define NOVM (void)0

__global__ __launch_bounds__(512, 2) void gemm_gates8(const unsigned short* __restrict__ A,
                                                      const unsigned short* __restrict__ W,
                                                      const float* __restrict__ bias,
                                                      unsigned short* __restrict__ C) {
    constexpr int K = K_DIM;
    constexpr int NT = K / 64;       // 32 K-tiles
    constexpr int NI = NT / 2;       // 16 iterations
    extern __shared__ unsigned short smem[];   // A: [0,32768) B: [32768,65536) ushorts

    const int tid = threadIdx.x;
    const int bid = blockIdx.x;                 // 640 blocks (32 x 20), %8==0
    const int swz = (bid & 7) * 80 + (bid >> 3);
    const int tm = swz / 20;
    const int tn = swz % 20;
    const int Arow0 = tm * 256;
    const int Brow0 = tn * 256;

    const int lane = tid & 63;
    const int wid = tid >> 6;
    const int wr = wid >> 2;        // 0..1 (M)
    const int wc = wid & 3;         // 0..3 (N)
    const int l31 = lane & 31;
    const int lhi = lane >> 5;      // 0..1
    const int bHalf = wc >> 1;
    const int swzl = (lane & 7) << 4;

    // LDS read byte offsets (within a half), pre-swizzled, gks=0
    int aRdS[2], bRdS[2];
#pragma unroll
    for (int m = 0; m < 2; ++m)
        aRdS[m] = (((wr * 64 + m * 32 + l31) * 128) + lhi * 16) ^ swzl;
#pragma unroll
    for (int n = 0; n < 2; ++n)
        bRdS[n] = ((((wc & 1) * 64 + n * 32 + l31) * 128) + lhi * 16) ^ swzl;

    // staging: linear LDS dest, inverse-swizzled global source (Rule 21)
    size_t aSrc[2], bSrc[2];
    int ldsDst[2];
#pragma unroll
    for (int l = 0; l < 2; ++l) {
        const int off = (l * 512 + tid) * 16;       // byte off within a 16KB half
        const int r = off >> 7;                     // row 0..127
        const int offS = off ^ ((r & 7) << 4);
        const int cb = (offS & 127) >> 1;           // element col 0..63
        aSrc[l] = (size_t)(Arow0 + r) * K + cb;
        bSrc[l] = (size_t)(Brow0 + r) * K + cb;
        ldsDst[l] = (l * 512 + tid) * 8;            // ushort idx within a half
    }

    auto stageA = [&](int buf, int half, int kt) {
#pragma unroll
        for (int l = 0; l < 2; ++l)
            __builtin_amdgcn_global_load_lds(
                (cg_void*)(A + aSrc[l] + (size_t)half * 128 * K + kt * 64),
                (lds_void*)(&smem[(buf * 2 + half) * 8192 + ldsDst[l]]), 16, 0, 0);
    };
    auto stageB = [&](int buf, int half, int kt) {
#pragma unroll
        for (int l = 0; l < 2; ++l)
            __builtin_amdgcn_global_load_lds(
                (cg_void*)(W + bSrc[l] + (size_t)half * 128 * K + kt * 64),
                (lds_void*)(&smem[32768 + (buf * 2 + half) * 8192 + ldsDst[l]]), 16, 0, 0);
    };

    f32x16 acc[8] = {};   // [h*4 + m*2 + n]

    // prologue: tile0 full + tile1.B0,B1 (12 loads), land tile0
    stageA(0, 0, 0); stageA(0, 1, 0); stageB(0, 0, 0); stageB(0, 1, 0);
    stageB(1, 0, 1); stageB(1, 1, 1);
    VMC4;
    asm volatile("" ::: "memory");
    __builtin_amdgcn_s_barrier();
    asm volatile("" ::: "memory");

    for (int i = 0; i < NI; ++i) {
        const int t1 = 2 * i + 1;
        const int t2 = (2 * i + 2) & (NT - 1);
        const int t3 = (2 * i + 3) & (NT - 1);
        bf16x8 bF[4][2];
        PH32(0, 0, 0, 1, { stageA(1, 0, t1); stageA(1, 1, t1); }, NOVM);   // P1
        PH32(0, 0, 1, 1, ;, NOVM);                                          // P2
        PH32(0, 1, 0, 0, { stageA(0, 0, t2); }, NOVM);                      // P3
        PH32(0, 1, 1, 0, { stageB(0, 0, t2); }, VMC4);                      // P4
        PH32(1, 0, 0, 1, { stageA(0, 1, t2); stageB(0, 1, t2); }, NOVM);    // P5
        PH32(1, 0, 1, 1, ;, NOVM);                                          // P6
        PH32(1, 1, 0, 0, { stageB(1, 0, t3); }, NOVM);                      // P7
        PH32(1, 1, 1, 0, { stageB(1, 1, t3); }, VMC4);                      // P8
    }

    // epilogue: bias + bf16 store (32-lane col-contiguous -> full 64B lines)
    const int crowBase = Arow0 + wr * 64;
    const int ccol = Brow0 + wc * 64;
    const int lrow = lhi * 4;
#pragma unroll
    for (int ni = 0; ni < 2; ++ni) {
        const int c = ccol + ni * 32 + l31;
        const float bvv = bias[c];
#pragma unroll
        for (int hh = 0; hh < 2; ++hh)
#pragma unroll
            for (int mi = 0; mi < 2; ++mi) {
                const int rbase = crowBase + hh * 128 + mi * 32 + lrow;
#pragma unroll
                for (int reg = 0; reg < 16; ++reg) {
                    const int row = rbase + (reg & 3) + 8 * (reg >> 2);
                    C[(size_t)row * NG + c] = f2bf(acc[hh * 4 + mi * 2 + ni][reg] + bvv);
                }
            }
    }
}

// ---------------- GEMM2 + fused epilogue: h_new ----------------
__global__ __launch_bounds__(256) void gemm_out(const unsigned short* __restrict__ A,     // inp2 [8192][2048]
                                                const unsigned short* __restrict__ W,     // Wu  [1024][2048]
                                                const float* __restrict__ bias,           // bu [1024]
                                                const unsigned short* __restrict__ gates, // [8192][5120]
                                                const float* __restrict__ x, const float* __restrict__ h,
                                                float* __restrict__ out) {                // [8192][1024]
    constexpr int K = K_DIM, N = D_DIM;
    __shared__ __attribute__((aligned(16))) unsigned short As[2][128 * 32];
    __shared__ __attribute__((aligned(16))) unsigned short Bs[2][128 * 32];
    const int tid = threadIdx.x;
    const int bid = blockIdx.x;                  // 512 blocks
    const int swz = (bid & 7) * 64 + (bid >> 3);
    const int tn = swz & 7;
    const int tm = swz >> 3;
    const size_t arow0 = (size_t)tm * 128;
    const size_t brow0 = (size_t)tn * 128;

    const int lane = tid & 63;
    const int wid = tid >> 6;
    const int wr = wid >> 1, wc = wid & 1;
    const int fr = lane & 15;
    const int kb = lane >> 4;
    const int aoff = (wr * 64 + fr) * 32 + kb * 8;
    const int boff = (wc * 64 + fr) * 32 + kb * 8;

    f32x4 acc[4][4] = {};

    auto stage = [&](int buf, int k0) {
#pragma unroll
        for (int r = 0; r < 2; ++r) {
            const int idx = r * 256 + tid;
            __builtin_amdgcn_global_load_lds(
                (cg_void*)(A + (arow0 + (idx >> 2)) * K + k0 + (idx & 3) * 8),
                (lds_void*)(&As[buf][idx * 8]), 16, 0, 0);
        }
#pragma unroll
        for (int r = 0; r < 2; ++r) {
            const int idx = r * 256 + tid;
            __builtin_amdgcn_global_load_lds(
                (cg_void*)(W + (brow0 + (idx >> 2)) * K + k0 + (idx & 3) * 8),
                (lds_void*)(&Bs[buf][idx * 8]), 16, 0, 0);
        }
    };

    stage(0, 0);
    __syncthreads();
    int cur = 0;
    constexpr int NT = K / 32;
    for (int t = 0; t < NT; ++t) {
        if (t + 1 < NT) stage(cur ^ 1, (t + 1) * 32);
        bf16x8 af[4], bv[4];
#pragma unroll
        for (int m = 0; m < 4; ++m) af[m] = *reinterpret_cast<const bf16x8*>(&As[cur][aoff + m * 512]);
#pragma unroll
        for (int n = 0; n < 4; ++n) bv[n] = *reinterpret_cast<const bf16x8*>(&Bs[cur][boff + n * 512]);
#pragma unroll
        for (int m = 0; m < 4; ++m)
#pragma unroll
            for (int n = 0; n < 4; ++n)
                acc[m][n] = __builtin_amdgcn_mfma_f32_16x16x32_bf16(af[m], bv[n], acc[m][n], 0, 0, 0);
        __syncthreads();
        cur ^= 1;
    }

    const size_t crow0 = arow0 + wr * 64;
    const int ccol0 = (int)brow0 + wc * 64;
#pragma unroll
    for (int n = 0; n < 4; ++n) {
        const int c = ccol0 + n * 16 + fr;
        const float bvv = bias[c];
#pragma unroll
        for (int m = 0; m < 4; ++m) {
            const size_t r0 = crow0 + m * 16 + kb * 4;
#pragma unroll
            for (int j = 0; j < 4; ++j) {
                const size_t r = r0 + j;
                const float u = tanhf(acc[m][n][j] + bvv);
                const size_t gb = r * NG + c;
                const float g2 = bf2f(gates[gb + 2 * D_DIM]);
                const float g3 = bf2f(gates[gb + 3 * D_DIM]);
                const float g4 = bf2f(gates[gb + 4 * D_DIM]);
                const float mx = fmaxf(fmaxf(g2, g3), g4);
                const float e2 = __expf(g2 - mx), e3 = __expf(g3 - mx), e4 = __expf(g4 - mx);
                const float zi = 1.0f / (e2 + e3 + e4);
                const size_t xi = r * D_DIM + c;
                out[xi] = (x[xi] * e2 + h[xi] * e3 + u * e4) * zi;
            }
        }
    }
}

extern "C" void kernel_launch(void* const* d_in, const int* in_sizes, int n_in,
                              void* d_out, int out_size, void* d_ws, size_t ws_size,
                              hipStream_t stream) {
    const float* x    = (const float*)d_in[0];
    const float* h    = (const float*)d_in[1];
    const float* ln_w = (const float*)d_in[2];
    const float* ln_b = (const float*)d_in[3];
    const float* ln2_w= (const float*)d_in[4];
    const float* ln2_b= (const float*)d_in[5];
    const float* Wg   = (const float*)d_in[6];
    const float* bg   = (const float*)d_in[7];
    const float* Wu   = (const float*)d_in[8];
    const float* bu   = (const float*)d_in[9];
    float* out = (float*)d_out;

    char* ws = (char*)d_ws;
    unsigned short* inp   = (unsigned short*)(ws);                                   // [8192][2048] (reused as inp2)
    unsigned short* Wg_b  = (unsigned short*)(ws + 33554432);                        // [5120][2048]
    unsigned short* Wu_b  = (unsigned short*)(ws + 33554432 + 20971520);             // [1024][2048]
    unsigned short* gates = (unsigned short*)(ws + 33554432 + 20971520 + 4194304);   // [8192][5120]

    (void)hipFuncSetAttribute((const void*)gemm_gates8,
                              hipFuncAttributeMaxDynamicSharedMemorySize, 131072);

    cvt_f32_bf16<<<(5120 * 2048 / 4 + 255) / 256, 256, 0, stream>>>(Wg, Wg_b, 5120 * 2048 / 4);
    cvt_f32_bf16<<<(1024 * 2048 / 4 + 255) / 256, 256, 0, stream>>>(Wu, Wu_b, 1024 * 2048 / 4);
    ln1_kernel<<<8192, 256, 0, stream>>>(x, h, ln_w, ln_b, inp);
    gemm_gates8<<<640, 512, 131072, stream>>>(inp, Wg_b, bg, gates);
    gate_ln2_kernel<<<8192, 256, 0, stream>>>(x, h, gates, ln2_w, ln2_b, inp);
    gemm_out<<<512, 256, 0, stream>>>(inp, Wu_b, bu, gates, x, h, out);
}

// Round 4
// 329.049 us; speedup vs baseline: 1.0425x; 1.0425x over previous
//
#include <hip/hip_runtime.h>

typedef __attribute__((ext_vector_type(8))) __bf16 bf16x8;
typedef __attribute__((ext_vector_type(4))) float f32x4;

#define B_ROWS 8192
#define D_DIM  1024
#define K_DIM  2048
#define NG     5120

typedef const __attribute__((address_space(1))) void cg_void;
typedef __attribute__((address_space(3))) void lds_void;

__device__ __forceinline__ float bf2f(unsigned short u) {
    union { unsigned int ui; float f; } c; c.ui = ((unsigned int)u) << 16; return c.f;
}
__device__ __forceinline__ unsigned short f2bf(float f) {
    unsigned int u = __float_as_uint(f);
    unsigned int r = u + 0x7fffu + ((u >> 16) & 1u);
    return (unsigned short)(r >> 16);
}
__device__ __forceinline__ float sigm(float v) { return 1.0f / (1.0f + __expf(-v)); }

// ---------------- weight f32 -> bf16 convert (both weights, one launch) ----------------
__global__ __launch_bounds__(256) void cvt2_f32_bf16(const float* __restrict__ wg,
                                                     const float* __restrict__ wu,
                                                     unsigned short* __restrict__ og,
                                                     unsigned short* __restrict__ ou) {
    const int NG4 = 5120 * 2048 / 4;       // 2,621,440
    const int NU4 = 1024 * 2048 / 4;       // 524,288
    int i = blockIdx.x * 256 + threadIdx.x;
    if (i < NG4) {
        float4 v = reinterpret_cast<const float4*>(wg)[i];
        ushort4 o; o.x = f2bf(v.x); o.y = f2bf(v.y); o.z = f2bf(v.z); o.w = f2bf(v.w);
        reinterpret_cast<ushort4*>(og)[i] = o;
    } else if (i < NG4 + NU4) {
        int j = i - NG4;
        float4 v = reinterpret_cast<const float4*>(wu)[j];
        ushort4 o; o.x = f2bf(v.x); o.y = f2bf(v.y); o.z = f2bf(v.z); o.w = f2bf(v.w);
        reinterpret_cast<ushort4*>(ou)[j] = o;
    }
}

// ---------------- LN1: concat(x,h) -> layernorm -> bf16 ----------------
__global__ __launch_bounds__(256) void ln1_kernel(const float* __restrict__ x, const float* __restrict__ h,
                                                  const float* __restrict__ w, const float* __restrict__ b,
                                                  unsigned short* __restrict__ out) {
    const int row = blockIdx.x;
    const int t = threadIdx.x;
    const float4 xv = reinterpret_cast<const float4*>(x + (size_t)row * D_DIM)[t];
    const float4 hv = reinterpret_cast<const float4*>(h + (size_t)row * D_DIM)[t];
    float s  = xv.x + xv.y + xv.z + xv.w + hv.x + hv.y + hv.z + hv.w;
    float s2 = xv.x*xv.x + xv.y*xv.y + xv.z*xv.z + xv.w*xv.w
             + hv.x*hv.x + hv.y*hv.y + hv.z*hv.z + hv.w*hv.w;
#pragma unroll
    for (int off = 32; off > 0; off >>= 1) { s += __shfl_xor(s, off); s2 += __shfl_xor(s2, off); }
    __shared__ float red[8];
    const int wid = t >> 6, lane = t & 63;
    if (lane == 0) { red[wid] = s; red[4 + wid] = s2; }
    __syncthreads();
    s  = red[0] + red[1] + red[2] + red[3];
    s2 = red[4] + red[5] + red[6] + red[7];
    const float mu  = s * (1.0f / K_DIM);
    const float var = s2 * (1.0f / K_DIM) - mu * mu;
    const float inv = rsqrtf(var + 1e-5f);
    const float4 w0 = reinterpret_cast<const float4*>(w)[t];
    const float4 b0 = reinterpret_cast<const float4*>(b)[t];
    const float4 w1 = reinterpret_cast<const float4*>(w + D_DIM)[t];
    const float4 b1 = reinterpret_cast<const float4*>(b + D_DIM)[t];
    ushort4 o0, o1;
    o0.x = f2bf((xv.x - mu) * inv * w0.x + b0.x);
    o0.y = f2bf((xv.y - mu) * inv * w0.y + b0.y);
    o0.z = f2bf((xv.z - mu) * inv * w0.z + b0.z);
    o0.w = f2bf((xv.w - mu) * inv * w0.w + b0.w);
    o1.x = f2bf((hv.x - mu) * inv * w1.x + b1.x);
    o1.y = f2bf((hv.y - mu) * inv * w1.y + b1.y);
    o1.z = f2bf((hv.z - mu) * inv * w1.z + b1.z);
    o1.w = f2bf((hv.w - mu) * inv * w1.w + b1.w);
    reinterpret_cast<ushort4*>(out + (size_t)row * K_DIM)[t] = o0;
    reinterpret_cast<ushort4*>(out + (size_t)row * K_DIM + D_DIM)[t] = o1;
}

// ---------------- gate sigmoid + LN2 -> bf16 inp2 ----------------
__global__ __launch_bounds__(256) void gate_ln2_kernel(const float* __restrict__ x, const float* __restrict__ h,
                                                       const unsigned short* __restrict__ gates,
                                                       const float* __restrict__ w, const float* __restrict__ b,
                                                       unsigned short* __restrict__ out) {
    const int row = blockIdx.x;
    const int t = threadIdx.x;
    const float4 xv = reinterpret_cast<const float4*>(x + (size_t)row * D_DIM)[t];
    const float4 hv = reinterpret_cast<const float4*>(h + (size_t)row * D_DIM)[t];
    const ushort4 g0v = reinterpret_cast<const ushort4*>(gates + (size_t)row * NG)[t];
    const ushort4 g1v = reinterpret_cast<const ushort4*>(gates + (size_t)row * NG + D_DIM)[t];
    float a0 = xv.x * sigm(bf2f(g0v.x));
    float a1 = xv.y * sigm(bf2f(g0v.y));
    float a2 = xv.z * sigm(bf2f(g0v.z));
    float a3 = xv.w * sigm(bf2f(g0v.w));
    float c0 = hv.x * sigm(bf2f(g1v.x));
    float c1 = hv.y * sigm(bf2f(g1v.y));
    float c2 = hv.z * sigm(bf2f(g1v.z));
    float c3 = hv.w * sigm(bf2f(g1v.w));
    float s  = a0 + a1 + a2 + a3 + c0 + c1 + c2 + c3;
    float s2 = a0*a0 + a1*a1 + a2*a2 + a3*a3 + c0*c0 + c1*c1 + c2*c2 + c3*c3;
#pragma unroll
    for (int off = 32; off > 0; off >>= 1) { s += __shfl_xor(s, off); s2 += __shfl_xor(s2, off); }
    __shared__ float red[8];
    const int wid = t >> 6, lane = t & 63;
    if (lane == 0) { red[wid] = s; red[4 + wid] = s2; }
    __syncthreads();
    s  = red[0] + red[1] + red[2] + red[3];
    s2 = red[4] + red[5] + red[6] + red[7];
    const float mu  = s * (1.0f / K_DIM);
    const float var = s2 * (1.0f / K_DIM) - mu * mu;
    const float inv = rsqrtf(var + 1e-5f);
    const float4 w0 = reinterpret_cast<const float4*>(w)[t];
    const float4 b0 = reinterpret_cast<const float4*>(b)[t];
    const float4 w1 = reinterpret_cast<const float4*>(w + D_DIM)[t];
    const float4 b1 = reinterpret_cast<const float4*>(b + D_DIM)[t];
    ushort4 o0, o1;
    o0.x = f2bf((a0 - mu) * inv * w0.x + b0.x);
    o0.y = f2bf((a1 - mu) * inv * w0.y + b0.y);
    o0.z = f2bf((a2 - mu) * inv * w0.z + b0.z);
    o0.w = f2bf((a3 - mu) * inv * w0.w + b0.w);
    o1.x = f2bf((c0 - mu) * inv * w1.x + b1.x);
    o1.y = f2bf((c1 - mu) * inv * w1.y + b1.y);
    o1.z = f2bf((c2 - mu) * inv * w1.z + b1.z);
    o1.w = f2bf((c3 - mu) * inv * w1.w + b1.w);
    reinterpret_cast<ushort4*>(out + (size_t)row * K_DIM)[t] = o0;
    reinterpret_cast<ushort4*>(out + (size_t)row * K_DIM + D_DIM)[t] = o1;
}

// ---------------- GEMM1: 256x256 8-phase pipelined (round-2 core) + 2-tile packing ----
// 512 blocks: bid<128 -> tiles {bid, bid+512}; else tile {bid}. Heavy blocks first.
// Per-tile pipeline identical to the race-verified round-2 kernel; vmcnt(0)+barrier
// drain between tiles kills wrapped in-flight stage loads before LDS reuse.
#define PH(BUF, H, KQ, LOADB, STAGE_CODE, VMCNT_CODE) do {                                            \
    bf16x8 aF[4];                                                                                     \
    _Pragma("unroll")                                                                                 \
    for (int m = 0; m < 4; ++m)                                                                       \
        aF[m] = *reinterpret_cast<const bf16x8*>(                                                     \
            &smem[((BUF) * 2 + (H)) * 8192 + ((aRdS[m] ^ ((KQ) * 64)) >> 1)]);                        \
    if (LOADB) {                                                                                      \
        _Pragma("unroll")                                                                             \
        for (int n = 0; n < 4; ++n)                                                                   \
            bF[KQ][n] = *reinterpret_cast<const bf16x8*>(                                             \
                &smem[32768 + ((BUF) * 2 + bHalf) * 8192 + ((bRdS[n] ^ ((KQ) * 64)) >> 1)]);          \
    }                                                                                                 \
    STAGE_CODE;                                                                                       \
    VMCNT_CODE;                                                                                       \
    asm volatile("" ::: "memory");                                                                    \
    __builtin_amdgcn_s_barrier();                                                                     \
    asm volatile("" ::: "memory");                                                                    \
    __builtin_amdgcn_s_setprio(1);                                                                    \
    _Pragma("unroll")                                                                                 \
    for (int m = 0; m < 4; ++m)                                                                       \
        _Pragma("unroll")                                                                             \
        for (int n = 0; n < 4; ++n)                                                                   \
            acc[(H) * 4 + m][n] =                                                                     \
                __builtin_amdgcn_mfma_f32_16x16x32_bf16(aF[m], bF[KQ][n], acc[(H) * 4 + m][n], 0, 0, 0);\
    __builtin_amdgcn_s_setprio(0);                                                                    \
    asm volatile("" ::: "memory");                                                                    \
    __builtin_amdgcn_s_barrier();                                                                     \
    asm volatile("" ::: "memory");                                                                    \
} while (0)

#define VMC4 asm volatile("s_waitcnt vmcnt(4)" ::: "memory")
#define VMC0 asm volatile("s_waitcnt vmcnt(0)" ::: "memory")
#define NOVM (void)0

__global__ __launch_bounds__(512, 2) void gemm_gates8(const unsigned short* __restrict__ A,
                                                      const unsigned short* __restrict__ W,
                                                      const float* __restrict__ bias,
                                                      unsigned short* __restrict__ C) {
    constexpr int K = K_DIM;
    constexpr int NT = K / 64;       // 32 K-tiles
    constexpr int NI = NT / 2;       // 16 iterations
    extern __shared__ unsigned short smem[];   // A: [0,32768) B: [32768,65536) ushorts

    const int tid = threadIdx.x;
    const int bid = blockIdx.x;                 // 512 blocks; 640 tiles
    const int lane = tid & 63;
    const int wid = tid >> 6;
    const int wr = wid >> 2;        // 0..1 (M)
    const int wc = wid & 3;         // 0..3 (N)
    const int fr = lane & 15;
    const int kb = lane >> 4;
    const int bHalf = wc >> 1;
    const int swzl = (fr & 7) << 4;

    // LDS read byte offsets (within a half), pre-swizzled, kq=0 (tile-independent)
    int aRdS[4], bRdS[4];
#pragma unroll
    for (int m = 0; m < 4; ++m)
        aRdS[m] = (((wr * 64 + m * 16 + fr) * 128) + kb * 16) ^ swzl;
#pragma unroll
    for (int n = 0; n < 4; ++n)
        bRdS[n] = ((((wc & 1) * 64 + n * 16 + fr) * 128) + kb * 16) ^ swzl;

    // staging geometry (tile-independent parts)
    int srcRow[2], srcCol[2], ldsDst[2];
#pragma unroll
    for (int l = 0; l < 2; ++l) {
        const int off = (l * 512 + tid) * 16;       // byte off within a 16KB half
        const int r = off >> 7;                     // row 0..127
        const int offS = off ^ ((r & 7) << 4);
        srcRow[l] = r;
        srcCol[l] = (offS & 127) >> 1;              // element col 0..63
        ldsDst[l] = (l * 512 + tid) * 8;            // ushort idx within a half
    }

    const int nrep = (bid < 128) ? 2 : 1;
    for (int rep = 0; rep < nrep; ++rep) {
        const int tile = bid + rep * 512;
        const int swz = (tile & 7) * 80 + (tile >> 3);
        const int tm = swz / 20;
        const int tn = swz % 20;
        const int Arow0 = tm * 256;
        const int Brow0 = tn * 256;

        size_t aSrc[2], bSrc[2];
#pragma unroll
        for (int l = 0; l < 2; ++l) {
            aSrc[l] = (size_t)(Arow0 + srcRow[l]) * K + srcCol[l];
            bSrc[l] = (size_t)(Brow0 + srcRow[l]) * K + srcCol[l];
        }

        auto stageA = [&](int buf, int half, int kt) {
#pragma unroll
            for (int l = 0; l < 2; ++l)
                __builtin_amdgcn_global_load_lds(
                    (cg_void*)(A + aSrc[l] + (size_t)half * 128 * K + kt * 64),
                    (lds_void*)(&smem[(buf * 2 + half) * 8192 + ldsDst[l]]), 16, 0, 0);
        };
        auto stageB = [&](int buf, int half, int kt) {
#pragma unroll
            for (int l = 0; l < 2; ++l)
                __builtin_amdgcn_global_load_lds(
                    (cg_void*)(W + bSrc[l] + (size_t)half * 128 * K + kt * 64),
                    (lds_void*)(&smem[32768 + (buf * 2 + half) * 8192 + ldsDst[l]]), 16, 0, 0);
        };

        f32x4 acc[8][4] = {};

        // prologue: tile0 full + tile1.B0,B1 (12 loads), land tile0
        stageA(0, 0, 0); stageA(0, 1, 0); stageB(0, 0, 0); stageB(0, 1, 0);
        stageB(1, 0, 1); stageB(1, 1, 1);
        VMC4;
        asm volatile("" ::: "memory");
        __builtin_amdgcn_s_barrier();
        asm volatile("" ::: "memory");

        for (int i = 0; i < NI; ++i) {
            const int t1 = 2 * i + 1;
            const int t2 = (2 * i + 2) & (NT - 1);
            const int t3 = (2 * i + 3) & (NT - 1);
            bf16x8 bF[2][4];
            PH(0, 0, 0, 1, { stageA(1, 0, t1); stageA(1, 1, t1); }, NOVM);   // P1
            PH(0, 0, 1, 1, ;, NOVM);                                          // P2
            PH(0, 1, 0, 0, { stageA(0, 0, t2); }, NOVM);                      // P3
            PH(0, 1, 1, 0, { stageB(0, 0, t2); }, VMC4);                      // P4
            PH(1, 0, 0, 1, { stageA(0, 1, t2); stageB(0, 1, t2); }, NOVM);    // P5
            PH(1, 0, 1, 1, ;, NOVM);                                          // P6
            PH(1, 1, 0, 0, { stageB(1, 0, t3); }, NOVM);                      // P7
            PH(1, 1, 1, 0, { stageB(1, 1, t3); }, VMC4);                      // P8
        }

        // drain wrapped in-flight stage loads before LDS reuse / next tile
        VMC0;
        asm volatile("" ::: "memory");
        __builtin_amdgcn_s_barrier();
        asm volatile("" ::: "memory");

        // epilogue: bias + bf16 store
        const int crowBase = Arow0 + wr * 64;
        const int ccol = Brow0 + wc * 64;
#pragma unroll
        for (int n = 0; n < 4; ++n) {
            const int c = ccol + n * 16 + fr;
            const float bvv = bias[c];
#pragma unroll
            for (int hh = 0; hh < 2; ++hh)
#pragma unroll
                for (int m = 0; m < 4; ++m) {
                    const size_t r0 = (size_t)crowBase + hh * 128 + m * 16 + kb * 4;
#pragma unroll
                    for (int j = 0; j < 4; ++j)
                        C[(r0 + j) * NG + c] = f2bf(acc[hh * 4 + m][n][j] + bvv);
                }
        }
    }
}

// ---------------- GEMM2 + fused epilogue: h_new ----------------
__global__ __launch_bounds__(256) void gemm_out(const unsigned short* __restrict__ A,     // inp2 [8192][2048]
                                                const unsigned short* __restrict__ W,     // Wu  [1024][2048]
                                                const float* __restrict__ bias,           // bu [1024]
                                                const unsigned short* __restrict__ gates, // [8192][5120]
                                                const float* __restrict__ x, const float* __restrict__ h,
                                                float* __restrict__ out) {                // [8192][1024]
    constexpr int K = K_DIM, N = D_DIM;
    __shared__ __attribute__((aligned(16))) unsigned short As[2][128 * 32];
    __shared__ __attribute__((aligned(16))) unsigned short Bs[2][128 * 32];
    const int tid = threadIdx.x;
    const int bid = blockIdx.x;                  // 512 blocks
    const int swz = (bid & 7) * 64 + (bid >> 3);
    const int tn = swz & 7;
    const int tm = swz >> 3;
    const size_t arow0 = (size_t)tm * 128;
    const size_t brow0 = (size_t)tn * 128;

    const int lane = tid & 63;
    const int wid = tid >> 6;
    const int wr = wid >> 1, wc = wid & 1;
    const int fr = lane & 15;
    const int kb = lane >> 4;
    const int aoff = (wr * 64 + fr) * 32 + kb * 8;
    const int boff = (wc * 64 + fr) * 32 + kb * 8;

    f32x4 acc[4][4] = {};

    auto stage = [&](int buf, int k0) {
#pragma unroll
        for (int r = 0; r < 2; ++r) {
            const int idx = r * 256 + tid;
            __builtin_amdgcn_global_load_lds(
                (cg_void*)(A + (arow0 + (idx >> 2)) * K + k0 + (idx & 3) * 8),
                (lds_void*)(&As[buf][idx * 8]), 16, 0, 0);
        }
#pragma unroll
        for (int r = 0; r < 2; ++r) {
            const int idx = r * 256 + tid;
            __builtin_amdgcn_global_load_lds(
                (cg_void*)(W + (brow0 + (idx >> 2)) * K + k0 + (idx & 3) * 8),
                (lds_void*)(&Bs[buf][idx * 8]), 16, 0, 0);
        }
    };

    stage(0, 0);
    __syncthreads();
    int cur = 0;
    constexpr int NT = K / 32;
    for (int t = 0; t < NT; ++t) {
        if (t + 1 < NT) stage(cur ^ 1, (t + 1) * 32);
        bf16x8 af[4], bv[4];
#pragma unroll
        for (int m = 0; m < 4; ++m) af[m] = *reinterpret_cast<const bf16x8*>(&As[cur][aoff + m * 512]);
#pragma unroll
        for (int n = 0; n < 4; ++n) bv[n] = *reinterpret_cast<const bf16x8*>(&Bs[cur][boff + n * 512]);
#pragma unroll
        for (int m = 0; m < 4; ++m)
#pragma unroll
            for (int n = 0; n < 4; ++n)
                acc[m][n] = __builtin_amdgcn_mfma_f32_16x16x32_bf16(af[m], bv[n], acc[m][n], 0, 0, 0);
        __syncthreads();
        cur ^= 1;
    }

    const size_t crow0 = arow0 + wr * 64;
    const int ccol0 = (int)brow0 + wc * 64;
#pragma unroll
    for (int n = 0; n < 4; ++n) {
        const int c = ccol0 + n * 16 + fr;
        const float bvv = bias[c];
#pragma unroll
        for (int m = 0; m < 4; ++m) {
            const size_t r0 = crow0 + m * 16 + kb * 4;
#pragma unroll
            for (int j = 0; j < 4; ++j) {
                const size_t r = r0 + j;
                const float u = tanhf(acc[m][n][j] + bvv);
                const size_t gb = r * NG + c;
                const float g2 = bf2f(gates[gb + 2 * D_DIM]);
                const float g3 = bf2f(gates[gb + 3 * D_DIM]);
                const float g4 = bf2f(gates[gb + 4 * D_DIM]);
                const float mx = fmaxf(fmaxf(g2, g3), g4);
                const float e2 = __expf(g2 - mx), e3 = __expf(g3 - mx), e4 = __expf(g4 - mx);
                const float zi = 1.0f / (e2 + e3 + e4);
                const size_t xi = r * D_DIM + c;
                out[xi] = (x[xi] * e2 + h[xi] * e3 + u * e4) * zi;
            }
        }
    }
}

extern "C" void kernel_launch(void* const* d_in, const int* in_sizes, int n_in,
                              void* d_out, int out_size, void* d_ws, size_t ws_size,
                              hipStream_t stream) {
    const float* x    = (const float*)d_in[0];
    const float* h    = (const float*)d_in[1];
    const float* ln_w = (const float*)d_in[2];
    const float* ln_b = (const float*)d_in[3];
    const float* ln2_w= (const float*)d_in[4];
    const float* ln2_b= (const float*)d_in[5];
    const float* Wg   = (const float*)d_in[6];
    const float* bg   = (const float*)d_in[7];
    const float* Wu   = (const float*)d_in[8];
    const float* bu   = (const float*)d_in[9];
    float* out = (float*)d_out;

    char* ws = (char*)d_ws;
    unsigned short* inp   = (unsigned short*)(ws);                                   // [8192][2048] (reused as inp2)
    unsigned short* Wg_b  = (unsigned short*)(ws + 33554432);                        // [5120][2048]
    unsigned short* Wu_b  = (unsigned short*)(ws + 33554432 + 20971520);             // [1024][2048]
    unsigned short* gates = (unsigned short*)(ws + 33554432 + 20971520 + 4194304);   // [8192][5120]

    (void)hipFuncSetAttribute((const void*)gemm_gates8,
                              hipFuncAttributeMaxDynamicSharedMemorySize, 131072);

    const int nCvt4 = 5120 * 2048 / 4 + 1024 * 2048 / 4;
    cvt2_f32_bf16<<<(nCvt4 + 255) / 256, 256, 0, stream>>>(Wg, Wu, Wg_b, Wu_b);
    ln1_kernel<<<8192, 256, 0, stream>>>(x, h, ln_w, ln_b, inp);
    gemm_gates8<<<512, 512, 131072, stream>>>(inp, Wg_b, bg, gates);
    gate_ln2_kernel<<<8192, 256, 0, stream>>>(x, h, gates, ln2_w, ln2_b, inp);
    gemm_out<<<512, 256, 0, stream>>>(inp, Wu_b, bu, gates, x, h, out);
}